// Round 10
// baseline (946.644 us; speedup 1.0000x reference)
//
#include <hip/hip_runtime.h>
#include <float.h>

// MAM dense, fused. C[m,n] = max_k(A[m,k]*W[n,k]) + min_k + bias[n] + arg
// indices (numpy first-occurrence).
//
// R10 (on R5's 670us; R9 measured the VGPR=128 allocation-quantum cliff):
// Window P=32 = full chunk (R0's chunk-tracking semantics) WITHOUT holding
// A in registers:
//  - c[i][j]/d[i][j] chains span the whole 32-k chunk, seeded from vmax at
//    h=0 (c = max3(vmax, q0.x, q0.y)); ONE cmp+csel per side per chunk ->
//    tracking 0.125 inst/product; total 1.625 (R5: 2.0, R9: 1.75).
//  - Register delta vs R5: +32 (c/d) ~ 108 VGPR -- same side of the 128
//    quantum as R5's 76 -> occupancy unchanged (~31%). R9's 140 VGPR
//    crossed the quantum -> 11.7% occupancy, -40% wall. VGPR<=128 is the
//    gate.
//  - 4x4 tile, quad-major LDS (R5 exact): per buf A[quad8][row64][4f] @0,
//    W[quad8][row64][4f] @8192, buf stride 16384, 32KB total; every
//    ds_read = base + compile-time imm, 0 conflicts (R5 measured).
//  - DMA global_load_lds width=16 linear dest (R5 exact ISSUE).
//  - Epilogue: per output/side ascending 32-k rescan from global
//    (A/W tiles L2-resident; R9 proved no FETCH blowup), bitwise-identical
//    products (plain mul == pk_mul, proven R3-R9).

typedef float f32x2 __attribute__((ext_vector_type(2)));
typedef float f32x4 __attribute__((ext_vector_type(4)));

#define BM 64
#define BN 64
#define BK 32

__device__ __forceinline__ f32x2 pk_mul(f32x2 a, f32x2 b) {
  f32x2 d;
  asm("v_pk_mul_f32 %0, %1, %2" : "=v"(d) : "v"(a), "v"(b));
  return d;
}
__device__ __forceinline__ float vmax3(float a, float b, float c) {
  float d;
  asm("v_max3_f32 %0, %1, %2, %3" : "=v"(d) : "v"(a), "v"(b), "v"(c));
  return d;
}
__device__ __forceinline__ float vmin3(float a, float b, float c) {
  float d;
  asm("v_min3_f32 %0, %1, %2, %3" : "=v"(d) : "v"(a), "v"(b), "v"(c));
  return d;
}

#define GLOAD16(gp, lp)                                                \
  __builtin_amdgcn_global_load_lds(                                    \
      (const __attribute__((address_space(1))) unsigned int*)(gp),     \
      (__attribute__((address_space(3))) unsigned int*)(lp), 16, 0, 0)

__global__ __launch_bounds__(256)
void mam_fused(const float* __restrict__ A, const float* __restrict__ W,
               const float* __restrict__ bias,
               float* __restrict__ out_v, float* __restrict__ out_ax,
               float* __restrict__ out_an, int M, int N, int K) {
  // [buf:2][mat:2 (A,W)][quad:8][row:64][4 floats] = 32768 B
  __shared__ __align__(16) unsigned char pool[32768];

  const int tid = threadIdx.x;
  const int tx = tid & 15;  // n-group: cols tx, tx+16, tx+32, tx+48
  const int ty = tid >> 4;  // m-group: rows ty*4 .. ty*4+3
  const int m0 = blockIdx.y * BM;
  const int n0 = blockIdx.x * BN;

  // ---- DMA mapping: lane ln = row, wave wv covers quads 2wv, 2wv+1 ----
  const int wv = tid >> 6;
  const int ln = tid & 63;
  int gra = m0 + ln; gra = gra < M ? gra : M - 1;
  int grw = n0 + ln; grw = grw < N ? grw : N - 1;
  const float* srcA = A + (size_t)gra * K + wv * 8;
  const float* srcW = W + (size_t)grw * K + wv * 8;
  const unsigned dmabase = (unsigned)wv * 2048u;

#define ISSUE(CH, BUF)                                                 \
  {                                                                    \
    const float* _sa = srcA + (CH)*BK;                                 \
    const float* _sw = srcW + (CH)*BK;                                 \
    unsigned char* _d = pool + (BUF)*16384u + dmabase;                 \
    GLOAD16(_sa, _d);                                                  \
    GLOAD16(_sa + 4, _d + 1024);                                       \
    GLOAD16(_sw, _d + 8192);                                           \
    GLOAD16(_sw + 4, _d + 9216);                                       \
  }

  // ---- accumulators ----
  float vmax[4][4], vmin[4][4];
  int pmax[4][4], pmin[4][4];  // chunk index of first occurrence (0..31)
#pragma unroll
  for (int i = 0; i < 4; ++i)
#pragma unroll
    for (int j = 0; j < 4; ++j) {
      vmax[i][j] = -FLT_MAX;
      vmin[i][j] = FLT_MAX;
      pmax[i][j] = 0;
      pmin[i][j] = 0;
    }

  const int nchunk = K / BK;

  // A read: quad q, row ty*4+i -> byte q*1024 + (ty*4+i)*16
  // W read: quad q, row tx+16j -> byte 8192 + q*1024 + tx*16 + j*256
#define ARD(KQ, I) (*(const f32x4*)(Ab + (KQ)*1024 + (I)*16))
#define WRD(KQ, J) (*(const f32x4*)(Wb + (KQ)*1024 + (J)*256))

  // ---- main loop: DMA double-buffered, one barrier per chunk ----
  ISSUE(0, 0)
  __syncthreads();
  int buf = 0;
  for (int ch = 0; ch < nchunk; ++ch) {
    if (ch + 1 < nchunk) ISSUE(ch + 1, buf ^ 1)
    const unsigned char* Ab = pool + (unsigned)buf * 16384u + ty * 64;
    const unsigned char* Wb = pool + (unsigned)buf * 16384u + 8192u + tx * 16;

    float c[4][4], d[4][4];  // chunk-local chains (seeded from vmax/vmin)
#pragma unroll
    for (int h = 0; h < 4; ++h) {  // quads 2h, 2h+1
      f32x4 a[4], b[4];
#pragma unroll
      for (int i = 0; i < 4; ++i) {
        a[i] = ARD(2 * h, i);
        b[i] = ARD(2 * h + 1, i);
      }
#pragma unroll
      for (int j = 0; j < 4; ++j) {
        const f32x4 w0 = WRD(2 * h, j);
        const f32x4 w1 = WRD(2 * h + 1, j);
#pragma unroll
        for (int i = 0; i < 4; ++i) {
          const f32x2 q0 = pk_mul(a[i].xy, w0.xy);
          const f32x2 q1 = pk_mul(a[i].zw, w0.zw);
          const f32x2 q2 = pk_mul(b[i].xy, w1.xy);
          const f32x2 q3 = pk_mul(b[i].zw, w1.zw);
          float cc = (h == 0) ? vmax3(vmax[i][j], q0.x, q0.y)
                              : vmax3(c[i][j], q0.x, q0.y);
          float dd = (h == 0) ? vmin3(vmin[i][j], q0.x, q0.y)
                              : vmin3(d[i][j], q0.x, q0.y);
          cc = vmax3(cc, q1.x, q1.y);
          dd = vmin3(dd, q1.x, q1.y);
          cc = vmax3(cc, q2.x, q2.y);
          dd = vmin3(dd, q2.x, q2.y);
          cc = vmax3(cc, q3.x, q3.y);
          dd = vmin3(dd, q3.x, q3.y);
          c[i][j] = cc;
          d[i][j] = dd;
        }
      }
    }
    // per-chunk tracking: c >= vmax always (seeded from it); != means improved
#pragma unroll
    for (int i = 0; i < 4; ++i)
#pragma unroll
      for (int j = 0; j < 4; ++j) {
        pmax[i][j] = (c[i][j] != vmax[i][j]) ? ch : pmax[i][j];
        vmax[i][j] = c[i][j];
        pmin[i][j] = (d[i][j] != vmin[i][j]) ? ch : pmin[i][j];
        vmin[i][j] = d[i][j];
      }
    __syncthreads();
    buf ^= 1;
  }

  // ---- epilogue: values + within-chunk argmax from global (L2-hot) ----
#pragma unroll
  for (int i = 0; i < 4; ++i) {
    const int gm = m0 + ty * 4 + i;
    if (gm >= M) continue;
    const size_t arow = (size_t)gm * K;
#pragma unroll
    for (int j = 0; j < 4; ++j) {
      const int gn = n0 + tx + 16 * j;
      if (gn >= N) continue;
      const size_t wrow = (size_t)gn * K;
      const size_t base = (size_t)gm * N + gn;
      out_v[base] = vmax[i][j] + vmin[i][j] + bias[gn];
      {  // max side: ascending 32-k scan of the winning chunk
        const int kb = pmax[i][j] * BK;
        const float* ap = A + arow + kb;
        const float* wp = W + wrow + kb;
        float cur = -FLT_MAX;
        int pos = 0;
#pragma unroll
        for (int g = 0; g < 8; ++g) {
          const f32x4 av = *(const f32x4*)(ap + g * 4);
          const f32x4 wvv = *(const f32x4*)(wp + g * 4);
          float p;
          p = av.x * wvv.x; if (p > cur) { cur = p; pos = g * 4 + 0; }
          p = av.y * wvv.y; if (p > cur) { cur = p; pos = g * 4 + 1; }
          p = av.z * wvv.z; if (p > cur) { cur = p; pos = g * 4 + 2; }
          p = av.w * wvv.w; if (p > cur) { cur = p; pos = g * 4 + 3; }
        }
        out_ax[base] = (float)(kb + pos);
      }
      {  // min side
        const int kb = pmin[i][j] * BK;
        const float* ap = A + arow + kb;
        const float* wp = W + wrow + kb;
        float cur = FLT_MAX;
        int pos = 0;
#pragma unroll
        for (int g = 0; g < 8; ++g) {
          const f32x4 av = *(const f32x4*)(ap + g * 4);
          const f32x4 wvv = *(const f32x4*)(wp + g * 4);
          float p;
          p = av.x * wvv.x; if (p < cur) { cur = p; pos = g * 4 + 0; }
          p = av.y * wvv.y; if (p < cur) { cur = p; pos = g * 4 + 1; }
          p = av.z * wvv.z; if (p < cur) { cur = p; pos = g * 4 + 2; }
          p = av.w * wvv.w; if (p < cur) { cur = p; pos = g * 4 + 3; }
        }
        out_an[base] = (float)(kb + pos);
      }
    }
  }
}

extern "C" void kernel_launch(void* const* d_in, const int* in_sizes, int n_in,
                              void* d_out, int out_size, void* d_ws, size_t ws_size,
                              hipStream_t stream) {
  const float* A = (const float*)d_in[0];     // [M, K] fp32
  const float* W = (const float*)d_in[1];     // [N, K] fp32
  const float* bias = (const float*)d_in[2];  // [N]    fp32
  const int N = in_sizes[2];
  const int K = in_sizes[1] / N;
  const int M = in_sizes[0] / K;
  float* out_v = (float*)d_out;
  float* out_ax = out_v + (size_t)M * N;
  float* out_an = out_v + 2 * (size_t)M * N;
  dim3 grid((N + BN - 1) / BN, (M + BM - 1) / BM);
  mam_fused<<<grid, dim3(256), 0, stream>>>(A, W, bias, out_v, out_ax, out_an,
                                            M, N, K);
}